// Round 5
// baseline (470.533 us; speedup 1.0000x reference)
//
#include <hip/hip_runtime.h>
#include <hip/hip_bf16.h>
#include <cstdint>

#define EPS_BN 1e-5f

typedef __attribute__((ext_vector_type(8)))  short bf16x8;   // 8 bf16 = 4 VGPRs
typedef __attribute__((ext_vector_type(16))) float f32x16;   // MFMA 32x32 acc
typedef __attribute__((ext_vector_type(4)))  unsigned short u16x4;

#define MFMA32(a, b, c) __builtin_amdgcn_mfma_f32_32x32x16_bf16(a, b, c, 0, 0, 0)

// async global->LDS, 16B/lane: per-lane GLOBAL src, LDS dst = uniform base + lane*16
#define GLOAD_LDS16(gsrc, ldst) \
    __builtin_amdgcn_global_load_lds((const __attribute__((address_space(1))) void*)(gsrc), \
                                     (__attribute__((address_space(3))) void*)(ldst), 16, 0, 0)

// ---------------------------------------------------------------------------
// build transposed inverted map: invT[k*n_down + s] = g  (s unique per k).
// Table pre-memset to 0xFF (-1 = miss).
// ---------------------------------------------------------------------------
__global__ void build_inv(const int* __restrict__ gather, const int* __restrict__ scatter,
                          long total, int m, int* __restrict__ invT, int n_down) {
    long i = (long)blockIdx.x * blockDim.x + threadIdx.x;
    if (i >= total) return;
    int s = scatter[i];
    if (s < n_down) {
        int k = (int)(i / m);
        invT[(long)k * n_down + s] = gather[i];
    }
}

// feat f32[n_in][32] -> bf16 [n_in+1][32] (pad row zero); also zero ybf pad row.
__global__ void fcvt(const float* __restrict__ f, unsigned short* __restrict__ fb,
                     unsigned short* __restrict__ ybf_pad, long n_in) {
    long t = (long)blockIdx.x * blockDim.x + threadIdx.x;
    long e = t * 4;
    long total = n_in * 32;
    if (e < total) {
        float4 v = *(const float4*)(f + e);
        u16x4 o;
        __hip_bfloat16 h;
        h = __float2bfloat16(v.x); o.x = *(unsigned short*)&h;
        h = __float2bfloat16(v.y); o.y = *(unsigned short*)&h;
        h = __float2bfloat16(v.z); o.z = *(unsigned short*)&h;
        h = __float2bfloat16(v.w); o.w = *(unsigned short*)&h;
        *(u16x4*)(fb + e) = o;
    } else if (e < total + 32) {
        u16x4 z = {0, 0, 0, 0};
        *(u16x4*)(fb + e) = z;
    }
    if (blockIdx.x == 0 && threadIdx.x < 16) {
        u16x4 z = {0, 0, 0, 0};
        ((u16x4*)ybf_pad)[threadIdx.x] = z;
    }
}

// w_ref f32[81][64cin][64cout] -> bf16 wt2[k][kq(4)][n(2)][lhi(2)][l31(32)][8]
// so a LINEAR LDS copy gives conflict-free lane-consecutive b128 B-frag reads:
// frag(kq,n) @ byte kq*2048 + n*1024 + lane*16.
__global__ void wcvt_r(const float* __restrict__ w, unsigned short* __restrict__ wt) {
    int e = blockIdx.x * 256 + threadIdx.x;      // 81*4096
    int k = e >> 12, r = e & 4095;
    int kq  = r >> 10;
    int n   = (r >> 9) & 1;
    int lhi = (r >> 8) & 1;
    int l31 = (r >> 3) & 31;
    int j   = r & 7;
    int cin  = (kq << 4) + (lhi << 3) + j;
    int cout = (n << 5) + l31;
    __hip_bfloat16 h = __float2bfloat16(w[(k << 12) + (cin << 6) + cout]);
    wt[e] = *(unsigned short*)&h;
}

// w_down f32[16][32cin][64cout] -> bf16 wtd[k][kq(2)][col(64)][16]
__global__ void wcvt_d(const float* __restrict__ w, unsigned short* __restrict__ wt) {
    int e = blockIdx.x * 256 + threadIdx.x;      // 16*2048
    int k = e >> 11, r = e & 2047;
    int cin = ((r >> 10) << 4) + (r & 15);
    int col = (r >> 4) & 63;
    __hip_bfloat16 h = __float2bfloat16(w[(k << 11) + (cin << 6) + col]);
    wt[e] = *(unsigned short*)&h;
}

// ---------------------------------------------------------------------------
// Stage 1: MFMA bf16, K=32, one wave = 32 rows. 91% pad-row gathers (L1-hot).
// ---------------------------------------------------------------------------
__global__ __launch_bounds__(256, 4) void conv_down_mfma(
        const unsigned short* __restrict__ fb, const unsigned short* __restrict__ wtd,
        const int* __restrict__ invd,
        const float* __restrict__ gamma, const float* __restrict__ beta,
        const float* __restrict__ mean, const float* __restrict__ var,
        unsigned short* __restrict__ y, int n_down, int n_in) {
    int  tid  = threadIdx.x;
    int  lane = tid & 63, l31 = lane & 31, lhi = lane >> 5;
    long wv   = ((long)blockIdx.x * 256 + tid) >> 6;
    long o0   = wv * 32;
    if (o0 >= n_down) return;

    int  oA = (int)(o0 + l31 < n_down ? o0 + l31 : n_down - 1);
    bool vA = (o0 + l31) < n_down;
    const short* ysb = (const short*)fb;

#define LDI_D(k) (vA ? invd[(size_t)(k) * n_down + oA] : -1)
#define GATH_D(dst, g) { \
        const short* p = ysb + (size_t)((g) < 0 ? n_in : (g)) * 32 + lhi * 8; \
        dst[0] = *(const bf16x8*)p; dst[1] = *(const bf16x8*)(p + 16); }

    int g0 = LDI_D(0), gq1 = LDI_D(1), gq2 = LDI_D(2);
    bf16x8 ac[2];
    GATH_D(ac, g0);
    f32x16 acc0 = {}, acc1 = {};
    const short* wp = (const short*)wtd + l31 * 16 + lhi * 8;

    for (int k = 0; k < 16; ++k) {
        int gN = (k < 13) ? LDI_D(k + 3) : -1;
        bf16x8 an[2];
        GATH_D(an, gq1);
        const short* wk = wp + k * 2048;
#pragma unroll
        for (int kq = 0; kq < 2; ++kq) {
            bf16x8 b0 = *(const bf16x8*)(wk + kq * 1024);
            bf16x8 b1 = *(const bf16x8*)(wk + kq * 1024 + 512);
            acc0 = MFMA32(ac[kq], b0, acc0);
            acc1 = MFMA32(ac[kq], b1, acc1);
        }
        ac[0] = an[0]; ac[1] = an[1];
        gq1 = gq2; gq2 = gN;
    }

#pragma unroll
    for (int n = 0; n < 2; ++n) {
        int col = n * 32 + l31;
        float iv = gamma[col] * rsqrtf(var[col] + EPS_BN);
        float bb = beta[col] - mean[col] * iv;
        const f32x16& A = n ? acc1 : acc0;
#pragma unroll
        for (int i = 0; i < 16; ++i) {
            long oo = o0 + (i & 3) + 8 * (i >> 2) + 4 * lhi;
            if (oo < n_down) {
                __hip_bfloat16 h = __float2bfloat16(fmaxf(A[i] * iv + bb, 0.f));
                y[oo * 64 + col] = *(unsigned short*)&h;
            }
        }
    }
#undef LDI_D
#undef GATH_D
}

// ---------------------------------------------------------------------------
// Stage 2: MFMA bf16, wave = 64 rows x 64 cols, 81 offsets.
// A: per-wave double-buffered LDS gather via global_load_lds (swizzled src).
// B: BLOCK-shared double-buffered LDS (each wave stages 2KB/region) -> B L2
//    traffic /4. Sync: counted vmcnt(11) + two raw s_barriers per region
//    (m201 discipline; never vmcnt(0) in-loop). idx->shfl chain hoisted one
//    region early (gi[8]). setprio around the MFMA cluster (T5).
// LDS: 4*16KB (A) + 16KB (B) = 80KB -> 2 blocks/CU.
// ---------------------------------------------------------------------------
__global__ __launch_bounds__(256, 2) void conv_ref_mfma(
        const unsigned short* __restrict__ ybf, const unsigned short* __restrict__ wt,
        const int* __restrict__ invr,
        const float* __restrict__ gamma, const float* __restrict__ beta,
        const float* __restrict__ mean, const float* __restrict__ var,
        float* __restrict__ out, int n_down, int nwg) {
    __shared__ char ldsA[4][2][8192];            // [wave][buf][64 rows x 128B]
    __shared__ char ldsB[2][8192];               // [buf][block-shared W[k]]

    // bijective XCD swizzle (m204)
    int bid = blockIdx.x;
    int q = nwg >> 3, r = nwg & 7;
    int xcd = bid & 7, pos = bid >> 3;
    int swzb = (xcd < r ? xcd * (q + 1) : r * (q + 1) + (xcd - r) * q) + pos;

    const int tid  = threadIdx.x;
    const int lane = tid & 63, l31 = lane & 31, lhi = lane >> 5;
    const int wid  = tid >> 6;
    const long o0  = ((long)swzb * 4 + wid) * 64;        // may exceed n_down (tail): clamped below

    const int oL = (int)(o0 + lane < n_down ? o0 + lane : n_down - 1);
    const char* ybase = (const char*)ybf;
    const char* wt_b  = (const char*)wt;
    char* ldsw = &ldsA[wid][0][0];
    // A-stage source swizzle: instr i covers rows i*8+(lane>>3); col slot (lane&7) ^ (row&7)
    const int swz = (((lane & 7) ^ (lane >> 3)) << 4);

    int gi[8];                                   // next-region stage rows (bperm-hoisted)
#define BPERM(gv) \
    _Pragma("unroll") \
    for (int i = 0; i < 8; ++i) gi[i] = __shfl((gv), (i << 3) + (lane >> 3));

#define STAGE_A(buf) \
    _Pragma("unroll") \
    for (int i = 0; i < 8; ++i) { \
        size_t grow = (size_t)(gi[i] < 0 ? n_down : gi[i]); \
        GLOAD_LDS16(ybase + grow * 128 + swz, ldsw + (buf) * 8192 + i * 1024); }

#define STAGE_B(buf, kk) { \
        const char* src = wt_b + (size_t)(kk) * 8192 + wid * 2048; \
        GLOAD_LDS16(src + lane * 16,        &ldsB[buf][wid * 2048]); \
        GLOAD_LDS16(src + 1024 + lane * 16, &ldsB[buf][wid * 2048 + 1024]); }

    // A-frag swizzled offsets
    const int rsw  = (l31 & 7) << 4;
    const int rowA = l31 * 128, rowB = (32 + l31) * 128;
    const int lhi16 = lhi * 16;

#define COMPUTE(buf) { \
        const char* la = ldsw + (buf) * 8192; \
        const char* lb = &ldsB[buf][0]; \
        __builtin_amdgcn_s_setprio(1); \
        _Pragma("unroll") \
        for (int kq = 0; kq < 4; ++kq) { \
            int fo = (kq * 32 + lhi16) ^ rsw; \
            bf16x8 aA = *(const bf16x8*)(la + rowA + fo); \
            bf16x8 aB = *(const bf16x8*)(la + rowB + fo); \
            bf16x8 b0 = *(const bf16x8*)(lb + kq * 2048 + lane * 16); \
            bf16x8 b1 = *(const bf16x8*)(lb + kq * 2048 + 1024 + lane * 16); \
            acc0 = MFMA32(aA, b0, acc0); \
            acc1 = MFMA32(aA, b1, acc1); \
            acc2 = MFMA32(aB, b0, acc2); \
            acc3 = MFMA32(aB, b1, acc3); } \
        __builtin_amdgcn_s_setprio(0); }

    f32x16 acc0 = {}, acc1 = {}, acc2 = {}, acc3 = {};

    // prologue: idx 0..3, stage A[0]/B[0] -> buf0, gi <- rows(g1)
    int ga  = invr[oL];
    int gb  = invr[(size_t)n_down + oL];
    int gS2 = invr[2 * (size_t)n_down + oL];
    int gS3 = invr[3 * (size_t)n_down + oL];
    asm volatile("s_waitcnt vmcnt(0)" ::: "memory");
    __builtin_amdgcn_sched_barrier(0);
    BPERM(ga);
    STAGE_A(0);
    STAGE_B(0, 0);
    BPERM(gb);

    for (int k = 0; k < 80; ++k) {
        const int cur = k & 1, nxt = cur ^ 1;
        STAGE_A(nxt);                             // A[k+1] (8 gload_lds)
        STAGE_B(nxt, k + 1);                      // B[k+1] (2 gload_lds)
        int gS4 = invr[(size_t)(k + 4) * n_down + oL];   // <= row 83 < 97 (reads invd region, unused)
        BPERM(gS2);                               // gi <- rows(g(k+2)) for next region
        asm volatile("s_waitcnt vmcnt(11)" ::: "memory");   // drain prev region's 11 -> A[k],B[k] done
        __builtin_amdgcn_sched_barrier(0);
        __builtin_amdgcn_s_barrier();             // all waves' B[k] slices visible
        COMPUTE(cur);
        __builtin_amdgcn_sched_barrier(0);
        __builtin_amdgcn_s_barrier();             // all waves done reading buf[cur] before next stage
        gS2 = gS3; gS3 = gS4;
    }
    asm volatile("s_waitcnt vmcnt(0)" ::: "memory");
    __builtin_amdgcn_sched_barrier(0);
    __builtin_amdgcn_s_barrier();
    COMPUTE(0);                                   // k = 80

    // epilogue: BN + ReLU, f32 out
#pragma unroll
    for (int m = 0; m < 2; ++m)
#pragma unroll
        for (int n = 0; n < 2; ++n) {
            int col = n * 32 + l31;
            float iv = gamma[col] * rsqrtf(var[col] + EPS_BN);
            float bb = beta[col] - mean[col] * iv;
            const f32x16& A = m == 0 ? (n == 0 ? acc0 : acc1) : (n == 0 ? acc2 : acc3);
#pragma unroll
            for (int i = 0; i < 16; ++i) {
                long oo = o0 + m * 32 + (i & 3) + 8 * (i >> 2) + 4 * lhi;
                if (oo < n_down)
                    out[oo * 64 + col] = fmaxf(A[i] * iv + bb, 0.f);
            }
        }
#undef BPERM
#undef STAGE_A
#undef STAGE_B
#undef COMPUTE
}

extern "C" void kernel_launch(void* const* d_in, const int* in_sizes, int n_args,
                              void* d_out, int out_size, void* d_ws, size_t ws_size,
                              hipStream_t stream) {
    const float* feat    = (const float*)d_in[0];
    const float* w_down  = (const float*)d_in[1];
    const float* gamma_d = (const float*)d_in[2];
    const float* beta_d  = (const float*)d_in[3];
    const float* mean_d  = (const float*)d_in[4];
    const float* var_d   = (const float*)d_in[5];
    const float* w_ref   = (const float*)d_in[6];
    const float* gamma_r = (const float*)d_in[7];
    const float* beta_r  = (const float*)d_in[8];
    const float* mean_r  = (const float*)d_in[9];
    const float* var_r   = (const float*)d_in[10];
    const int*   gather_d  = (const int*)d_in[11];
    const int*   scatter_d = (const int*)d_in[12];
    const int*   gather_r  = (const int*)d_in[13];
    const int*   scatter_r = (const int*)d_in[14];

    int n_in   = in_sizes[0] / 32;
    int md     = in_sizes[11] / 16;
    int mr     = in_sizes[13] / 81;
    int n_down = out_size / 64;

    // ws: ybf[(n_down+1)*64]bf16 | featbf[(n_in+1)*32]bf16 | wt[81*4096]bf16 |
    //     wtd[16*2048]bf16 | invr[81*n_down]i32 | invd[16*n_down]i32 (contig for memset)
    char* ws = (char*)d_ws;
    size_t off = 0;
    auto alloc = [&](size_t bytes) { char* p = ws + off; off = (off + bytes + 255) & ~(size_t)255; return p; };
    unsigned short* ybf    = (unsigned short*)alloc((size_t)(n_down + 1) * 64 * 2);
    unsigned short* featbf = (unsigned short*)alloc((size_t)(n_in + 1) * 32 * 2);
    unsigned short* wt     = (unsigned short*)alloc((size_t)81 * 4096 * 2);
    unsigned short* wtd    = (unsigned short*)alloc((size_t)16 * 2048 * 2);
    int* invr = (int*)(ws + off);
    int* invd = invr + (size_t)81 * n_down;

    hipMemsetAsync(invr, 0xFF, (size_t)97 * n_down * sizeof(int), stream);

    long td = 16L * md;
    build_inv<<<(int)((td + 255) / 256), 256, 0, stream>>>(gather_d, scatter_d, td, md, invd, n_down);
    long tr = 81L * mr;
    build_inv<<<(int)((tr + 255) / 256), 256, 0, stream>>>(gather_r, scatter_r, tr, mr, invr, n_down);

    long ft = ((long)n_in * 32 + 32) / 4;
    fcvt<<<(int)((ft + 255) / 256), 256, 0, stream>>>(feat, featbf, ybf + (size_t)n_down * 64, n_in);
    wcvt_r<<<81 * 4096 / 256, 256, 0, stream>>>(w_ref, wt);
    wcvt_d<<<16 * 2048 / 256, 256, 0, stream>>>(w_down, wtd);

    long wavesD  = ((long)n_down + 31) / 32;
    int  blocksD = (int)((wavesD * 64 + 255) / 256);
    conv_down_mfma<<<blocksD, 256, 0, stream>>>(featbf, wtd, invd,
                                                gamma_d, beta_d, mean_d, var_d,
                                                ybf, n_down, n_in);

    long wavesR  = ((long)n_down + 63) / 64;
    int  blocksR = (int)((wavesR + 3) / 4);
    conv_ref_mfma<<<blocksR, 256, 0, stream>>>(ybf, wt, invr,
                                               gamma_r, beta_r, mean_r, var_r,
                                               (float*)d_out, n_down, blocksR);
}